// Round 5
// baseline (287.702 us; speedup 1.0000x reference)
//
#include <hip/hip_runtime.h>
#include <math.h>

// QuantumIntegrator: r_embed [B=4, S=4096, 2] float32, dt [4] float32.
// Outputs (flat float32): r_final [4,4096,2] then score [4,4096,4096].
//
// R5: wave-per-row (no LDS, no __syncthreads, pure shuffle reduction) +
// non-temporal score stores. 268 MB fp32 score write floor ~41 us @ 6.6 TB/s.

#define S_LEN 4096
#define ROWS  16384   // B*S with B=4 (fixed by setup_inputs)
#define BLK   256     // 4 waves = 4 rows per block
#define EPSF  1e-6f
#define RATE  0.01f
#define MINR  0.1f
#define MAXR  2.0f

typedef float vf4 __attribute__((ext_vector_type(4)));

// In-wave reduction of 3 floats; result valid in lane 0.
__device__ __forceinline__ void wave_red3(float &a, float &b, float &c) {
    #pragma unroll
    for (int off = 32; off > 0; off >>= 1) {
        a += __shfl_down(a, off);
        b += __shfl_down(b, off);
        c += __shfl_down(c, off);
    }
}

// ws layout (floats): [0, 2*ROWS) r_mid; [2*ROWS, 4*ROWS) k1; [4*ROWS, 5*ROWS) sum_score.

__global__ __launch_bounds__(BLK) void k_pass1(
    const float2* __restrict__ r_in,              // fp32 (x,y) per (b,s)
    const float* __restrict__ dt_in,              // fp32 per batch
    float* __restrict__ ws,
    float* __restrict__ score_out)                // fp32, [ROWS, S_LEN]
{
    const int lane = threadIdx.x & 63;
    const int row  = (blockIdx.x << 2) + (threadIdx.x >> 6);   // wave-per-row
    const int b = row >> 12;
    const int s = row & (S_LEN - 1);
    const float2* rb  = r_in + ((size_t)b << 12);
    const vf4*    rb4 = (const vf4*)rb;           // one vf4 = points (2i, 2i+1)
    const float2  rs  = rb[s];

    // Triangular reduction: denom, numer. Coalesced 16B loads, L1-hot.
    float dsum = 0.f, nx = 0.f, ny = 0.f;
    for (int i = lane; 2*i <= s; i += 64) {
        vf4 p = rb4[i];
        float d0 = fmaxf(rs.x * p.x + rs.y * p.y, 0.f);   // t = 2i <= s
        dsum += d0; nx = fmaf(d0, p.x, nx); ny = fmaf(d0, p.y, ny);
        if (2*i + 1 <= s) {
            float d1 = fmaxf(rs.x * p.z + rs.y * p.w, 0.f);
            dsum += d1; nx = fmaf(d1, p.z, nx); ny = fmaf(d1, p.w, ny);
        }
    }
    wave_red3(dsum, nx, ny);
    const float D  = __shfl(dsum, 0);
    const float Nx = __shfl(nx, 0);
    const float Ny = __shfl(ny, 0);

    const float dc  = fmaxf(D, EPSF);
    const float inv = 1.f / dc;
    if (lane == 0) {
        const float dtb = dt_in[b];
        float k1x = dtb * Nx * inv;
        float k1y = dtb * Ny * inv;
        if (!isfinite(k1x)) k1x = 0.f;
        if (!isfinite(k1y)) k1y = 0.f;
        float rmx = rs.x + k1x, rmy = rs.y + k1y;
        if (!isfinite(rmx)) rmx = rs.x;
        if (!isfinite(rmy)) rmy = rs.y;
        float* rmid = ws;
        float* k1w  = ws + 2 * ROWS;
        float* s1w  = ws + 4 * ROWS;
        rmid[2*row]   = rmx; rmid[2*row+1] = rmy;
        k1w[2*row]    = k1x; k1w[2*row+1]  = k1y;
        s1w[row]      = D * inv;     // == sum of normalized score row
    }

    // Score row: 16 vf4 per lane; instruction j covers a contiguous 1 KB segment.
    const float isx = rs.x * inv, isy = rs.y * inv;  // relu(dot)*inv == relu(dot*inv), inv>0
    vf4* orow = (vf4*)(score_out + (size_t)row * S_LEN);
    #pragma unroll 4
    for (int j = 0; j < 16; j++) {
        const int i4 = lane + (j << 6);   // vf4 index within row
        const int t  = i4 << 2;           // first column of this vf4
        vf4 v = {0.f, 0.f, 0.f, 0.f};
        if (t <= s) {
            vf4 p01 = rb4[2*i4];          // points t, t+1
            vf4 p23 = rb4[2*i4 + 1];      // points t+2, t+3 (always in-bounds)
            v.x = fmaxf(isx * p01.x + isy * p01.y, 0.f);
            v.y = (t + 1 <= s) ? fmaxf(isx * p01.z + isy * p01.w, 0.f) : 0.f;
            v.z = (t + 2 <= s) ? fmaxf(isx * p23.x + isy * p23.y, 0.f) : 0.f;
            v.w = (t + 3 <= s) ? fmaxf(isx * p23.z + isy * p23.w, 0.f) : 0.f;
        }
        __builtin_nontemporal_store(v, orow + i4);   // streamed, never re-read
    }
}

__global__ __launch_bounds__(BLK) void k_pass2(
    const float2* __restrict__ r_in,
    const float* __restrict__ dt_in,
    const float* __restrict__ ws,
    float* __restrict__ rfinal_out)               // fp32, [ROWS, 2]
{
    const int lane = threadIdx.x & 63;
    const int row  = (blockIdx.x << 2) + (threadIdx.x >> 6);
    const int b = row >> 12;
    const int s = row & (S_LEN - 1);
    const float2* rm  = ((const float2*)ws) + ((size_t)b << 12);
    const vf4*    rm4 = (const vf4*)rm;
    const float2  rs  = rm[s];

    float dsum = 0.f, nx = 0.f, ny = 0.f;
    for (int i = lane; 2*i <= s; i += 64) {
        vf4 p = rm4[i];
        float d0 = fmaxf(rs.x * p.x + rs.y * p.y, 0.f);
        dsum += d0; nx = fmaf(d0, p.x, nx); ny = fmaf(d0, p.y, ny);
        if (2*i + 1 <= s) {
            float d1 = fmaxf(rs.x * p.z + rs.y * p.w, 0.f);
            dsum += d1; nx = fmaf(d1, p.z, nx); ny = fmaf(d1, p.w, ny);
        }
    }
    wave_red3(dsum, nx, ny);
    if (lane == 0) {
        const float* k1w = ws + 2 * ROWS;
        const float* s1w = ws + 4 * ROWS;
        const float dc = fmaxf(dsum, EPSF);
        const float dtb = dt_in[b];
        float k2x = dtb * nx / dc;
        float k2y = dtb * ny / dc;
        if (!isfinite(k2x)) k2x = 0.f;
        if (!isfinite(k2y)) k2y = 0.f;
        const float2 r0 = r_in[row];
        const float k1x = k1w[2*row], k1y = k1w[2*row+1];
        const float rnx = r0.x + 0.5f * (k1x + k2x);
        const float rny = r0.y + 0.5f * (k1y + k2y);
        const float nr = fmaxf(sqrtf(rnx*rnx + rny*rny), EPSF);
        const float ar = fminf(fmaxf(nr + s1w[row] * RATE, MINR), MAXR);
        const float sc = ar / nr;
        float fx = rnx * sc, fy = rny * sc;
        if (!isfinite(fx)) fx = r0.x;
        if (!isfinite(fy)) fy = r0.y;
        rfinal_out[2*row]   = fx;
        rfinal_out[2*row+1] = fy;
    }
}

extern "C" void kernel_launch(void* const* d_in, const int* in_sizes, int n_in,
                              void* d_out, int out_size, void* d_ws, size_t ws_size,
                              hipStream_t stream) {
    const float2* r_in  = (const float2*)d_in[0];   // fp32 [4,4096,2]
    const float*  dt_in = (const float*)d_in[1];    // fp32 [4]
    float* out = (float*)d_out;
    float* ws  = (float*)d_ws;

    // d_out: first ROWS*2 floats = r_final, then ROWS*S_LEN floats = score.
    float* rfinal_out = out;
    float* score_out  = out + (size_t)2 * ROWS;

    hipLaunchKernelGGL(k_pass1, dim3(ROWS / 4), dim3(BLK), 0, stream,
                       r_in, dt_in, ws, score_out);
    hipLaunchKernelGGL(k_pass2, dim3(ROWS / 4), dim3(BLK), 0, stream,
                       r_in, dt_in, ws, rfinal_out);
}